// Round 1
// baseline (2493.436 us; speedup 1.0000x reference)
//
#include <hip/hip_runtime.h>
#include <hip/hip_bf16.h>

// Problem constants
#define N_ANCH   589824     // 256*256*9
#define NBLK     2304       // N_ANCH / 256
#define TOPK     12000
#define KPAD     12032      // 188*64
#define NW       188        // mask words per row
#define OUTN     2000
#define CAP      32768      // candidate buffer capacity

// 9 base anchors (ratio-major, scale-minor), widths/heights (x1-x0+1)
__constant__ float c_aw[9] = {184.f, 368.f, 736.f, 128.f, 256.f, 512.f,  88.f, 176.f, 352.f};
__constant__ float c_ah[9] = { 96.f, 192.f, 384.f, 128.f, 256.f, 512.f, 176.f, 352.f, 704.f};

// Decode one anchor's proposal box exactly like the (non-fused fp32) reference.
__device__ __forceinline__ void decode_one(int i, const float4* __restrict__ delta,
                                           float4* box, bool* valid) {
#pragma clang fp contract(off)
    int a    = i % 9;
    int cell = i / 9;
    int gx = cell & 255;
    int gy = cell >> 8;
    float w = c_aw[a], h = c_ah[a];
    float cx = (float)gx * 16.0f + 8.0f;   // exact: anchor ctr = shift + 8.0
    float cy = (float)gy * 16.0f + 8.0f;
    float4 d = delta[i];
    float pcx = d.x * w + cx;
    float pcy = d.y * h + cy;
    float pw  = expf(d.z) * w;
    float ph  = expf(d.w) * h;
    float x0 = fminf(fmaxf(pcx - 0.5f * pw, 0.f), 4096.f);
    float y0 = fminf(fmaxf(pcy - 0.5f * ph, 0.f), 4096.f);
    float x1 = fminf(fmaxf(pcx + 0.5f * pw, 0.f), 4096.f);
    float y1 = fminf(fmaxf(pcy + 0.5f * ph, 0.f), 4096.f);
    *box = make_float4(x0, y0, x1, y1);
    *valid = (x1 - x0 >= 16.f) && (y1 - y0 >= 16.f);
}

// Zero the small control buffers and the output.
__global__ __launch_bounds__(256) void k_init(unsigned* hist1, unsigned* hist2,
                                              unsigned* ctrl, unsigned* sukey, float* out) {
    int t = blockIdx.x * 256 + threadIdx.x;
    if (t < 256) { hist1[t] = 0u; hist2[t] = 0u; }
    if (t < 16)  ctrl[t] = 0u;
    if (t < KPAD) sukey[t] = 0u;
    if (t < OUTN * 4) out[t] = 0.f;
}

// Decode all anchors, make validity-masked ordered score key, level-1 histogram.
__global__ __launch_bounds__(256) void k_score(const float4* __restrict__ delta,
                                               const float2* __restrict__ score,
                                               unsigned* __restrict__ ukey,
                                               unsigned* __restrict__ hist1) {
    __shared__ unsigned lh[256];
    lh[threadIdx.x] = 0u;
    __syncthreads();
    int i = blockIdx.x * 256 + threadIdx.x;
    float4 box; bool valid;
    decode_one(i, delta, &box, &valid);
    unsigned u = 0u;
    if (valid) {
        float s = score[i].y;
        unsigned b = __float_as_uint(s);
        u = (b & 0x80000000u) ? ~b : (b | 0x80000000u);  // order-preserving map; 0 = dead
    }
    ukey[i] = u;
    atomicAdd(&lh[u >> 24], 1u);
    __syncthreads();
    unsigned c = lh[threadIdx.x];
    if (c) atomicAdd(&hist1[threadIdx.x], c);
}

__global__ void k_scan1(const unsigned* __restrict__ hist1, unsigned* __restrict__ ctrl) {
    if (threadIdx.x != 0) return;
    unsigned acc = 0; int b = 255;
    for (; b > 0; --b) {
        unsigned c = hist1[b];
        if (acc + c >= (unsigned)TOPK) break;
        acc += c;
    }
    ctrl[0] = (unsigned)b;   // b1
    ctrl[1] = acc;           // count strictly above bucket b1
}

__global__ __launch_bounds__(256) void k_hist2(const unsigned* __restrict__ ukey,
                                               const unsigned* __restrict__ ctrl,
                                               unsigned* __restrict__ hist2) {
    __shared__ unsigned lh[256];
    lh[threadIdx.x] = 0u;
    __syncthreads();
    unsigned b1 = ctrl[0];
    int i = blockIdx.x * 256 + threadIdx.x;
    unsigned u = ukey[i];
    if ((u >> 24) == b1) atomicAdd(&lh[(u >> 16) & 255u], 1u);
    __syncthreads();
    unsigned c = lh[threadIdx.x];
    if (c) atomicAdd(&hist2[threadIdx.x], c);
}

__global__ void k_scan2(const unsigned* __restrict__ hist2, unsigned* __restrict__ ctrl) {
    if (threadIdx.x != 0) return;
    unsigned target = (unsigned)TOPK - ctrl[1];
    unsigned acc = 0; int b = 255;
    for (; b > 0; --b) {
        unsigned c = hist2[b];
        if (acc + c >= target) break;
        acc += c;
    }
    ctrl[2] = (ctrl[0] << 8) | (unsigned)b;  // 16-bit prefix threshold P
}

// Compact all items with prefix >= P (and alive) into candidate list.
__global__ __launch_bounds__(256) void k_compact(const unsigned* __restrict__ ukey,
                                                 const unsigned* __restrict__ ctrl,
                                                 unsigned* __restrict__ cnt,
                                                 unsigned long long* __restrict__ cand) {
    unsigned P = ctrl[2];
    int i = blockIdx.x * 256 + threadIdx.x;
    unsigned u = ukey[i];
    bool pred = (u != 0u) && ((u >> 16) >= P);
    unsigned long long m = __ballot(pred);
    if (m == 0ull) return;
    int lane = threadIdx.x & 63;
    int leader = __ffsll((unsigned long long)m) - 1;
    unsigned base = 0;
    if (lane == leader) base = atomicAdd(cnt, (unsigned)__popcll(m));
    base = __shfl(base, leader);
    if (pred) {
        unsigned long long below = m & ((1ull << lane) - 1ull);
        unsigned pos = base + (unsigned)__popcll(below);
        if (pos < CAP) cand[pos] = ((unsigned long long)u << 32) | (unsigned)(~i);
    }
}

// Exact rank of each candidate key (desc by score, asc by index); scatter top-K.
__global__ __launch_bounds__(256) void k_rank(const unsigned long long* __restrict__ cand,
                                              const unsigned* __restrict__ ctrl,
                                              unsigned* __restrict__ sukey,
                                              unsigned* __restrict__ sidx) {
    unsigned cnt = ctrl[3];
    int C = (int)(cnt < (unsigned)CAP ? cnt : (unsigned)CAP);
    if ((int)(blockIdx.x * 256) >= C) return;
    int t = blockIdx.x * 256 + threadIdx.x;
    unsigned long long mykey = (t < C) ? cand[t] : ~0ull;
    int rank = 0;
    __shared__ unsigned long long tile[256];
    for (int j0 = 0; j0 < C; j0 += 256) {
        int j = j0 + threadIdx.x;
        tile[threadIdx.x] = (j < C) ? cand[j] : 0ull;
        __syncthreads();
        int lim = (C - j0 < 256) ? (C - j0) : 256;
        #pragma unroll 4
        for (int jj = 0; jj < lim; ++jj) rank += (tile[jj] > mykey) ? 1 : 0;
        __syncthreads();
    }
    if (t < C && rank < TOPK) {
        sukey[rank] = (unsigned)(mykey >> 32);
        sidx[rank]  = ~(unsigned)mykey;
    }
}

// Decode boxes for the sorted top-K ranks (dead ranks -> zero box).
__global__ __launch_bounds__(256) void k_decode(const unsigned* __restrict__ sukey,
                                                const unsigned* __restrict__ sidx,
                                                const float4* __restrict__ delta,
                                                float4* __restrict__ sboxes) {
    int r = blockIdx.x * 256 + threadIdx.x;
    if (r >= KPAD) return;
    float4 box = make_float4(0.f, 0.f, 0.f, 0.f);
    if (sukey[r] != 0u) {
        bool v;
        decode_one((int)sidx[r], delta, &box, &v);
    }
    sboxes[r] = box;
}

// Suppression bitmask: bit j of mask[r][cb] set iff IoU(r, cb*64+j) > 0.7 and j != r.
// Only upper triangle (cb >= rb) is computed/used.
__global__ __launch_bounds__(64) void k_mask(const float4* __restrict__ sboxes,
                                             unsigned long long* __restrict__ mask) {
    int cb = blockIdx.x, rb = blockIdx.y;
    if (cb < rb) return;
    __shared__ float4 cbox[64];
    int tid = threadIdx.x;
    cbox[tid] = sboxes[cb * 64 + tid];
    __syncthreads();
    int r = rb * 64 + tid;
    float4 me = sboxes[r];
    float areaMe = (me.z - me.x) * (me.w - me.y);
    unsigned long long bits = 0ull;
    for (int j = 0; j < 64; ++j) {
        float4 o = cbox[j];
        float xx0 = fmaxf(me.x, o.x);
        float yy0 = fmaxf(me.y, o.y);
        float xx1 = fminf(me.z, o.z);
        float yy1 = fminf(me.w, o.w);
        float iw = fmaxf(xx1 - xx0, 0.f);
        float ih = fmaxf(yy1 - yy0, 0.f);
        float inter = iw * ih;
        float areaO = (o.z - o.x) * (o.w - o.y);
        float denom = fmaxf(areaMe + areaO - inter, 1e-8f);
        float iou = inter / denom;
        if (iou > 0.7f && (cb * 64 + j) != r) bits |= (1ull << j);
    }
    mask[(size_t)r * NW + cb] = bits;
}

// Serial greedy reduce: single wave, bitmask OR per kept box.
__global__ __launch_bounds__(64) void k_reduce(const float4* __restrict__ sboxes,
                                               const unsigned* __restrict__ sukey,
                                               const unsigned long long* __restrict__ mask,
                                               float4* __restrict__ out) {
    __shared__ unsigned long long removed[NW];
    int tid = threadIdx.x;
    // init: dead ranks (ukey==0) are pre-removed. Coalesced load + ballot per word.
    for (int w = 0; w < NW; ++w) {
        unsigned long long m = __ballot(sukey[w * 64 + tid] == 0u);
        if (tid == 0) removed[w] = m;
    }
    __syncthreads();
    int nkept = 0;
    for (int w = 0; w < NW; ++w) {
        unsigned long long avail = ~removed[w];
        while (avail) {
            int b = __ffsll(avail) - 1;
            int i = (w << 6) + b;
            if (tid == 0) out[nkept] = sboxes[i];
            ++nkept;
            if (nkept >= OUTN) return;
            const unsigned long long* row = mask + (size_t)i * NW;
            for (int w2 = w + tid; w2 < NW; w2 += 64) removed[w2] |= row[w2];
            __syncthreads();
            unsigned long long cur = removed[w];
            avail = (~cur) & ((b < 63) ? (~0ull << (b + 1)) : 0ull);
        }
    }
}

extern "C" void kernel_launch(void* const* d_in, const int* in_sizes, int n_in,
                              void* d_out, int out_size, void* d_ws, size_t ws_size,
                              hipStream_t stream) {
    const float4*  delta = (const float4*)d_in[0];
    const float2*  score = (const float2*)d_in[1];
    char* ws = (char*)d_ws;

    // Workspace layout (bytes)
    unsigned*            ukey  = (unsigned*)(ws + 0);                 // N_ANCH u32
    unsigned*            hist1 = (unsigned*)(ws + 2359296);           // 256
    unsigned*            hist2 = hist1 + 256;                         // 256
    unsigned*            ctrl  = hist2 + 256;                         // 16: b1, above1, P, cand_count
    unsigned long long*  cand  = (unsigned long long*)(ws + 2361600); // CAP u64
    unsigned*            sukey = (unsigned*)(ws + 2623744);           // KPAD u32
    unsigned*            sidx  = (unsigned*)(ws + 2671872);           // KPAD u32
    float4*              sbox  = (float4*)(ws + 2720000);             // KPAD f32x4
    unsigned long long*  mask  = (unsigned long long*)(ws + 2912512); // KPAD*NW u64

    k_init   <<<47,   256, 0, stream>>>(hist1, hist2, ctrl, sukey, (float*)d_out);
    k_score  <<<NBLK, 256, 0, stream>>>(delta, score, ukey, hist1);
    k_scan1  <<<1,    64,  0, stream>>>(hist1, ctrl);
    k_hist2  <<<NBLK, 256, 0, stream>>>(ukey, ctrl, hist2);
    k_scan2  <<<1,    64,  0, stream>>>(hist2, ctrl);
    k_compact<<<NBLK, 256, 0, stream>>>(ukey, ctrl, ctrl + 3, cand);
    k_rank   <<<CAP/256, 256, 0, stream>>>(cand, ctrl, sukey, sidx);
    k_decode <<<KPAD/256, 256, 0, stream>>>(sukey, sidx, delta, sbox);
    dim3 mgrid(NW, NW);
    k_mask   <<<mgrid, 64, 0, stream>>>(sbox, mask);
    k_reduce <<<1,    64,  0, stream>>>(sbox, sukey, mask, (float4*)d_out);
}

// Round 2
// 957.580 us; speedup vs baseline: 2.6039x; 2.6039x over previous
//
#include <hip/hip_runtime.h>
#include <hip/hip_bf16.h>

// Problem constants
#define N_ANCH   589824     // 256*256*9
#define NBLK     2304       // N_ANCH / 256
#define TOPK     12000
#define KPAD     12032      // 188*64
#define NW       188        // mask words per row
#define OUTN     2000
#define CAP      32768      // candidate buffer capacity

typedef unsigned long long u64;

// 9 base anchors (ratio-major, scale-minor), widths/heights (x1-x0+1)
__constant__ float c_aw[9] = {184.f, 368.f, 736.f, 128.f, 256.f, 512.f,  88.f, 176.f, 352.f};
__constant__ float c_ah[9] = { 96.f, 192.f, 384.f, 128.f, 256.f, 512.f, 176.f, 352.f, 704.f};

// Decode one anchor's proposal box exactly like the (non-fused fp32) reference.
__device__ __forceinline__ void decode_one(int i, const float4* __restrict__ delta,
                                           float4* box, bool* valid) {
#pragma clang fp contract(off)
    int a    = i % 9;
    int cell = i / 9;
    int gx = cell & 255;
    int gy = cell >> 8;
    float w = c_aw[a], h = c_ah[a];
    float cx = (float)gx * 16.0f + 8.0f;
    float cy = (float)gy * 16.0f + 8.0f;
    float4 d = delta[i];
    float pcx = d.x * w + cx;
    float pcy = d.y * h + cy;
    float pw  = expf(d.z) * w;
    float ph  = expf(d.w) * h;
    float x0 = fminf(fmaxf(pcx - 0.5f * pw, 0.f), 4096.f);
    float y0 = fminf(fmaxf(pcy - 0.5f * ph, 0.f), 4096.f);
    float x1 = fminf(fmaxf(pcx + 0.5f * pw, 0.f), 4096.f);
    float y1 = fminf(fmaxf(pcy + 0.5f * ph, 0.f), 4096.f);
    *box = make_float4(x0, y0, x1, y1);
    *valid = (x1 - x0 >= 16.f) && (y1 - y0 >= 16.f);
}

// Zero the small control buffers and the output.
__global__ __launch_bounds__(256) void k_init(unsigned* hist1, unsigned* hist2,
                                              unsigned* ctrl, unsigned* sukey, float* out) {
    int t = blockIdx.x * 256 + threadIdx.x;
    if (t < 256) { hist1[t] = 0u; hist2[t] = 0u; }
    if (t < 16)  ctrl[t] = 0u;
    if (t < KPAD) sukey[t] = 0u;
    if (t < OUTN * 4) out[t] = 0.f;
}

// Decode all anchors, make validity-masked ordered score key, level-1 histogram.
__global__ __launch_bounds__(256) void k_score(const float4* __restrict__ delta,
                                               const float2* __restrict__ score,
                                               unsigned* __restrict__ ukey,
                                               unsigned* __restrict__ hist1) {
    __shared__ unsigned lh[256];
    lh[threadIdx.x] = 0u;
    __syncthreads();
    int i = blockIdx.x * 256 + threadIdx.x;
    float4 box; bool valid;
    decode_one(i, delta, &box, &valid);
    unsigned u = 0u;
    if (valid) {
        float s = score[i].y;
        unsigned b = __float_as_uint(s);
        u = (b & 0x80000000u) ? ~b : (b | 0x80000000u);  // order-preserving map; 0 = dead
    }
    ukey[i] = u;
    atomicAdd(&lh[u >> 24], 1u);
    __syncthreads();
    unsigned c = lh[threadIdx.x];
    if (c) atomicAdd(&hist1[threadIdx.x], c);
}

// Wave-parallel radix select, level 1: find bucket b1 (bits 31:24) where the
// descending cumulative count crosses TOPK. 64 lanes, 4 buckets each.
__global__ __launch_bounds__(64) void k_scan1(const unsigned* __restrict__ hist1,
                                              unsigned* __restrict__ ctrl) {
    int lane = threadIdx.x;
    uint4 h = ((const uint4*)hist1)[lane];
    unsigned S = h.x + h.y + h.z + h.w;
#pragma unroll
    for (int d = 1; d < 64; d <<= 1) {
        unsigned t = __shfl_down(S, d);
        if (lane + d < 64) S += t;               // inclusive suffix sum over lanes
    }
    unsigned Snext = __shfl_down(S, 1);
    if (lane == 63) Snext = 0;
    unsigned suf3 = h.w + Snext;
    unsigned suf2 = h.z + suf3;
    unsigned suf1 = h.y + suf2;
    unsigned suf0 = h.x + suf1;                   // == S
    u64 qual = __ballot(suf0 >= (unsigned)TOPK);
    int L = 63 - __clzll(qual ? qual : 1ull);     // qual==0 -> L=0
    if (lane == L) {
        int k; unsigned sufk1;
        if      (suf3 >= (unsigned)TOPK) { k = 3; sufk1 = Snext; }
        else if (suf2 >= (unsigned)TOPK) { k = 2; sufk1 = suf3; }
        else if (suf1 >= (unsigned)TOPK) { k = 1; sufk1 = suf2; }
        else                             { k = 0; sufk1 = suf1; }
        int b = 4 * lane + k;
        if (qual == 0ull) { b = 0; sufk1 = suf1; }
        ctrl[0] = (unsigned)b;    // b1
        ctrl[1] = sufk1;          // count strictly above bucket b1
    }
}

__global__ __launch_bounds__(256) void k_hist2(const unsigned* __restrict__ ukey,
                                               const unsigned* __restrict__ ctrl,
                                               unsigned* __restrict__ hist2) {
    __shared__ unsigned lh[256];
    lh[threadIdx.x] = 0u;
    __syncthreads();
    unsigned b1 = ctrl[0];
    int i = blockIdx.x * 256 + threadIdx.x;
    unsigned u = ukey[i];
    if ((u >> 24) == b1) atomicAdd(&lh[(u >> 16) & 255u], 1u);
    __syncthreads();
    unsigned c = lh[threadIdx.x];
    if (c) atomicAdd(&hist2[threadIdx.x], c);
}

// Wave-parallel radix select, level 2: threshold on 16-bit prefix.
__global__ __launch_bounds__(64) void k_scan2(const unsigned* __restrict__ hist2,
                                              unsigned* __restrict__ ctrl) {
    int lane = threadIdx.x;
    unsigned target = (unsigned)TOPK - ctrl[1];
    uint4 h = ((const uint4*)hist2)[lane];
    unsigned S = h.x + h.y + h.z + h.w;
#pragma unroll
    for (int d = 1; d < 64; d <<= 1) {
        unsigned t = __shfl_down(S, d);
        if (lane + d < 64) S += t;
    }
    unsigned Snext = __shfl_down(S, 1);
    if (lane == 63) Snext = 0;
    unsigned suf3 = h.w + Snext;
    unsigned suf2 = h.z + suf3;
    unsigned suf1 = h.y + suf2;
    unsigned suf0 = h.x + suf1;
    u64 qual = __ballot(suf0 >= target);
    int L = 63 - __clzll(qual ? qual : 1ull);
    if (lane == L) {
        int k;
        if      (suf3 >= target) k = 3;
        else if (suf2 >= target) k = 2;
        else if (suf1 >= target) k = 1;
        else                     k = 0;
        int b = 4 * lane + k;
        if (qual == 0ull) b = 0;
        ctrl[2] = (ctrl[0] << 8) | (unsigned)b;   // 16-bit prefix threshold P
    }
}

// Compact all items with prefix >= P (and alive) into candidate list.
__global__ __launch_bounds__(256) void k_compact(const unsigned* __restrict__ ukey,
                                                 const unsigned* __restrict__ ctrl,
                                                 unsigned* __restrict__ cnt,
                                                 u64* __restrict__ cand) {
    unsigned P = ctrl[2];
    int i = blockIdx.x * 256 + threadIdx.x;
    unsigned u = ukey[i];
    bool pred = (u != 0u) && ((u >> 16) >= P);
    u64 m = __ballot(pred);
    if (m == 0ull) return;
    int lane = threadIdx.x & 63;
    int leader = __ffsll(m) - 1;
    unsigned base = 0;
    if (lane == leader) base = atomicAdd(cnt, (unsigned)__popcll(m));
    base = __shfl(base, leader);
    if (pred) {
        u64 below = m & ((1ull << lane) - 1ull);
        unsigned pos = base + (unsigned)__popcll(below);
        if (pos < CAP) cand[pos] = ((u64)u << 32) | (unsigned)(~i);
    }
}

// Exact rank of each candidate key (desc by score, asc by index); scatter top-K.
__global__ __launch_bounds__(256) void k_rank(const u64* __restrict__ cand,
                                              const unsigned* __restrict__ ctrl,
                                              unsigned* __restrict__ sukey,
                                              unsigned* __restrict__ sidx) {
    unsigned cnt = ctrl[3];
    int C = (int)(cnt < (unsigned)CAP ? cnt : (unsigned)CAP);
    if ((int)(blockIdx.x * 256) >= C) return;
    int t = blockIdx.x * 256 + threadIdx.x;
    u64 mykey = (t < C) ? cand[t] : ~0ull;
    int rank = 0;
    __shared__ u64 tile[256];
    for (int j0 = 0; j0 < C; j0 += 256) {
        int j = j0 + threadIdx.x;
        tile[threadIdx.x] = (j < C) ? cand[j] : 0ull;
        __syncthreads();
        int lim = (C - j0 < 256) ? (C - j0) : 256;
        #pragma unroll 4
        for (int jj = 0; jj < lim; ++jj) rank += (tile[jj] > mykey) ? 1 : 0;
        __syncthreads();
    }
    if (t < C && rank < TOPK) {
        sukey[rank] = (unsigned)(mykey >> 32);
        sidx[rank]  = ~(unsigned)mykey;
    }
}

// Decode boxes for the sorted top-K ranks (dead ranks -> zero box).
__global__ __launch_bounds__(256) void k_decode(const unsigned* __restrict__ sukey,
                                                const unsigned* __restrict__ sidx,
                                                const float4* __restrict__ delta,
                                                float4* __restrict__ sboxes) {
    int r = blockIdx.x * 256 + threadIdx.x;
    if (r >= KPAD) return;
    float4 box = make_float4(0.f, 0.f, 0.f, 0.f);
    if (sukey[r] != 0u) {
        bool v;
        decode_one((int)sidx[r], delta, &box, &v);
    }
    sboxes[r] = box;
}

// Suppression bitmask: bit j of mask[r][cb] set iff IoU(r, cb*64+j) > 0.7 and j != r.
// Only upper triangle (cb >= rb) is computed/used.
__global__ __launch_bounds__(64) void k_mask(const float4* __restrict__ sboxes,
                                             u64* __restrict__ mask) {
    int cb = blockIdx.x, rb = blockIdx.y;
    if (cb < rb) return;
    __shared__ float4 cbox[64];
    int tid = threadIdx.x;
    cbox[tid] = sboxes[cb * 64 + tid];
    __syncthreads();
    int r = rb * 64 + tid;
    float4 me = sboxes[r];
    float areaMe = (me.z - me.x) * (me.w - me.y);
    u64 bits = 0ull;
    for (int j = 0; j < 64; ++j) {
        float4 o = cbox[j];
        float xx0 = fmaxf(me.x, o.x);
        float yy0 = fmaxf(me.y, o.y);
        float xx1 = fminf(me.z, o.z);
        float yy1 = fminf(me.w, o.w);
        float iw = fmaxf(xx1 - xx0, 0.f);
        float ih = fmaxf(yy1 - yy0, 0.f);
        float inter = iw * ih;
        float areaO = (o.z - o.x) * (o.w - o.y);
        float denom = fmaxf(areaMe + areaO - inter, 1e-8f);
        float iou = inter / denom;
        if (iou > 0.7f && (cb * 64 + j) != r) bits |= (1ull << j);
    }
    mask[(size_t)r * NW + cb] = bits;
}

// Blocked greedy reduce: single wave, removed-bitmap in registers (3 words/lane,
// lane owns columns {lane, lane+64, lane+128}). Per 64-rank block: parallel diag
// load (prefetched), serial intra-block resolve via shfl, batched row ORs.
__global__ __launch_bounds__(64) void k_reduce(const float4* __restrict__ sboxes,
                                               const unsigned* __restrict__ ctrl,
                                               const u64* __restrict__ mask,
                                               float4* __restrict__ out) {
    int lane = threadIdx.x;
    unsigned cnt = ctrl[3];
    int C = (int)(cnt < (unsigned)CAP ? cnt : (unsigned)CAP);
    int nvalid = C < TOPK ? C : TOPK;

    // removed-bitmap init: tail ranks >= nvalid are pre-removed.
    auto initw = [&](int w) -> u64 {
        long long lo = (long long)w * 64;
        if (lo + 64 <= (long long)nvalid) return 0ull;
        if (lo >= (long long)nvalid) return ~0ull;
        return ~((1ull << (unsigned)(nvalid - lo)) - 1ull);
    };
    u64 r0 = initw(lane);
    u64 r1 = initw(lane + 64);
    u64 r2 = (lane + 128 < NW) ? initw(lane + 128) : ~0ull;

    int nblocks = (nvalid + 63) >> 6;
    if (nblocks == 0) return;

    int nkept = 0;
    // prefetch diag words of block 0: lane i holds mask[(0*64+i)][0]
    u64 dg = mask[(size_t)lane * NW + 0];

    for (int b = 0; b < nblocks; ++b) {
        u64 dg_cur = dg;
        int bn = (b + 1 < nblocks) ? b + 1 : b;
        dg = mask[((size_t)(bn * 64 + lane)) * NW + bn];   // prefetch next diag

        // current removed word for block b (owner: lane b&63, register b>>6)
        int part = b >> 6;
        u64 src = (part == 0) ? r0 : ((part == 1) ? r1 : r2);
        u64 rw = __shfl(src, b & 63);
        u64 avail = ~rw;
        if (!avail) continue;

        // serial greedy within block: one shfl per kept box
        u64 keptmask = 0ull;
        int kc = 0;
        while (avail) {
            int j = __ffsll(avail) - 1;
            keptmask |= (1ull << j);
            ++kc;
            avail &= ~(1ull << j);
            if (nkept + kc >= OUTN) break;
            u64 dj = __shfl(dg_cur, j);
            avail &= ~dj;
        }

        // parallel output store: lane l handles bit l
        if ((keptmask >> lane) & 1ull) {
            u64 below = keptmask & ((1ull << lane) - 1ull);
            int pos = nkept + (int)__popcll(below);
            if (pos < OUTN) out[pos] = sboxes[b * 64 + lane];
        }
        nkept += (int)__popcll(keptmask);
        if (nkept >= OUTN) break;

        // OR kept rows into register bitmap, 4 rows per batch for MLP
        int w2 = (lane + 128 < NW) ? lane + 128 : 0;
        u64 km = keptmask;
        while (km) {
            int j0 = __ffsll(km) - 1; km &= km - 1;
            int j1 = j0, j2 = j0, j3 = j0;
            if (km) { j1 = __ffsll(km) - 1; km &= km - 1; }
            if (km) { j2 = __ffsll(km) - 1; km &= km - 1; }
            if (km) { j3 = __ffsll(km) - 1; km &= km - 1; }
            const u64* rp0 = mask + (size_t)(b * 64 + j0) * NW;
            const u64* rp1 = mask + (size_t)(b * 64 + j1) * NW;
            const u64* rp2 = mask + (size_t)(b * 64 + j2) * NW;
            const u64* rp3 = mask + (size_t)(b * 64 + j3) * NW;
            u64 a0 = rp0[lane],      a1 = rp1[lane],      a2 = rp2[lane],      a3 = rp3[lane];
            u64 b0 = rp0[lane + 64], b1 = rp1[lane + 64], b2 = rp2[lane + 64], b3 = rp3[lane + 64];
            u64 c0 = rp0[w2],        c1 = rp1[w2],        c2 = rp2[w2],        c3 = rp3[w2];
            r0 |= a0 | a1 | a2 | a3;
            r1 |= b0 | b1 | b2 | b3;
            u64 cc = c0 | c1 | c2 | c3;
            r2 |= (lane + 128 < NW) ? cc : 0ull;
        }
    }
}

extern "C" void kernel_launch(void* const* d_in, const int* in_sizes, int n_in,
                              void* d_out, int out_size, void* d_ws, size_t ws_size,
                              hipStream_t stream) {
    const float4*  delta = (const float4*)d_in[0];
    const float2*  score = (const float2*)d_in[1];
    char* ws = (char*)d_ws;

    // Workspace layout (bytes)
    unsigned* ukey  = (unsigned*)(ws + 0);                 // N_ANCH u32
    unsigned* hist1 = (unsigned*)(ws + 2359296);           // 256
    unsigned* hist2 = hist1 + 256;                         // 256
    unsigned* ctrl  = hist2 + 256;                         // 16: b1, above1, P, cand_count
    u64*      cand  = (u64*)(ws + 2361600);                // CAP u64
    unsigned* sukey = (unsigned*)(ws + 2623744);           // KPAD u32
    unsigned* sidx  = (unsigned*)(ws + 2671872);           // KPAD u32
    float4*   sbox  = (float4*)(ws + 2720000);             // KPAD f32x4
    u64*      mask  = (u64*)(ws + 2912512);                // KPAD*NW u64

    k_init   <<<47,   256, 0, stream>>>(hist1, hist2, ctrl, sukey, (float*)d_out);
    k_score  <<<NBLK, 256, 0, stream>>>(delta, score, ukey, hist1);
    k_scan1  <<<1,    64,  0, stream>>>(hist1, ctrl);
    k_hist2  <<<NBLK, 256, 0, stream>>>(ukey, ctrl, hist2);
    k_scan2  <<<1,    64,  0, stream>>>(hist2, ctrl);
    k_compact<<<NBLK, 256, 0, stream>>>(ukey, ctrl, ctrl + 3, cand);
    k_rank   <<<CAP/256, 256, 0, stream>>>(cand, ctrl, sukey, sidx);
    k_decode <<<KPAD/256, 256, 0, stream>>>(sukey, sidx, delta, sbox);
    dim3 mgrid(NW, NW);
    k_mask   <<<mgrid, 64, 0, stream>>>(sbox, mask);
    k_reduce <<<1,    64,  0, stream>>>(sbox, ctrl, mask, (float4*)d_out);
}